// Round 3
// baseline (568.614 us; speedup 1.0000x reference)
//
#include <hip/hip_runtime.h>
#include <hip/hip_bf16.h>
#include <stdint.h>

using bf16 = __hip_bfloat16;
using bf16x8 = __attribute__((ext_vector_type(8))) short;   // 8 bf16 = 4 VGPRs
using f32x4  = __attribute__((ext_vector_type(4))) float;

#define AS1 __attribute__((address_space(1)))
#define AS3 __attribute__((address_space(3)))

__device__ __forceinline__ void async_ld16(const void* g, void* l) {
    __builtin_amdgcn_global_load_lds((const AS1 void*)g, (AS3 void*)l, 16, 0, 0);
}

__device__ __forceinline__ f32x4 mfma_bf16(bf16x8 a, bf16x8 b, f32x4 c) {
    return __builtin_amdgcn_mfma_f32_16x16x32_bf16(a, b, c, 0, 0, 0);
}

__device__ __forceinline__ float sexp(float x) {
    return __expf(fmaxf(x, -80.0f));
}

// ---- 16-lane-group reductions: DPP row_shr (VALU) + one broadcast swizzle ----
template<int N> __device__ __forceinline__ float dpp_max16(float x) {
    int xi = __builtin_bit_cast(int, x);
    int yi = __builtin_amdgcn_update_dpp(xi, xi, 0x110 | N, 0xf, 0xf, false);
    return fmaxf(x, __builtin_bit_cast(float, yi));
}
template<int N> __device__ __forceinline__ float dpp_add16(float x) {
    int xi = __builtin_bit_cast(int, x);
    int yi = __builtin_amdgcn_update_dpp(0, xi, 0x110 | N, 0xf, 0xf, true);
    return x + __builtin_bit_cast(float, yi);
}
__device__ __forceinline__ float bcast15(float x) {
    return __builtin_bit_cast(float,
        __builtin_amdgcn_ds_swizzle(__builtin_bit_cast(int, x), 0x01F0));
}
__device__ __forceinline__ float redmax16(float x) {
    x = dpp_max16<1>(x); x = dpp_max16<2>(x);
    x = dpp_max16<4>(x); x = dpp_max16<8>(x);
    return bcast15(x);
}
__device__ __forceinline__ float redsum16(float x) {
    x = dpp_add16<1>(x); x = dpp_add16<2>(x);
    x = dpp_add16<4>(x); x = dpp_add16<8>(x);
    return bcast15(x);
}

// ---------------------------------------------------------------------------
// Merged f32->bf16 converts
// ---------------------------------------------------------------------------
__device__ __forceinline__ void cvt8(const float* p, bf16* d) {
    float4 lo = *(const float4*)p;
    float4 hi = *(const float4*)(p + 4);
    bf16 t8[8] = {__float2bfloat16(lo.x), __float2bfloat16(lo.y),
                  __float2bfloat16(lo.z), __float2bfloat16(lo.w),
                  __float2bfloat16(hi.x), __float2bfloat16(hi.y),
                  __float2bfloat16(hi.z), __float2bfloat16(hi.w)};
    *(bf16x8*)d = *(const bf16x8*)t8;
}

__global__ __launch_bounds__(256) void cvt4_k(const float* __restrict__ x,  bf16* __restrict__ xb,
                                              const float* __restrict__ wq, bf16* __restrict__ wqb,
                                              const float* __restrict__ wk, bf16* __restrict__ wkb,
                                              const float* __restrict__ wv, bf16* __restrict__ wvb) {
    int stride = gridDim.x * blockDim.x;
    for (int u = blockIdx.x * blockDim.x + threadIdx.x; u < 4194304; u += stride) {
        const float* s; bf16* d; size_t off;
        if (u < 1048576)      { s = x;  d = xb;  off = (size_t)u * 8; }
        else if (u < 3145728) { s = wq; d = wqb; off = (size_t)(u - 1048576) * 8; }
        else if (u < 3670016) { s = wk; d = wkb; off = (size_t)(u - 3145728) * 8; }
        else                  { s = wv; d = wvb; off = (size_t)(u - 3670016) * 8; }
        cvt8(s + off, d + off);
    }
}

__global__ __launch_bounds__(256) void cvt_f32_bf16(const float* __restrict__ src,
                                                    bf16* __restrict__ dst, int n8) {
    int stride = gridDim.x * blockDim.x;
    for (int u = blockIdx.x * blockDim.x + threadIdx.x; u < n8; u += stride)
        cvt8(src + (size_t)u * 8, dst + (size_t)u * 8);
}

// ---------------------------------------------------------------------------
// OLD simple GEMM (kept only for the no-workspace fallback, f32 sources).
// ---------------------------------------------------------------------------
template<bool SRCF32>
__device__ __forceinline__ void stage_tile(const void* __restrict__ src,
                                           bf16* __restrict__ s,
                                           int row0, int K, int k0, int tid) {
    if constexpr (SRCF32) {
        const float* g = (const float*)src;
        #pragma unroll
        for (int i = 0; i < 2; ++i) {
            int u = tid + 256 * i;
            int row = u >> 2, c8 = (u & 3) * 8;
            cvt8(g + (size_t)(row0 + row) * K + k0 + c8, &s[row * 32 + c8]);
        }
    } else {
        const bf16* g = (const bf16*)src;
        const int wave = tid >> 6, lane = tid & 63;
        const int c0 = wave * 64 + lane;
        const int r0 = c0 >> 2, cb0 = (c0 & 3) * 16;
        const int c1 = 256 + c0;
        const int r1 = c1 >> 2, cb1 = (c1 & 3) * 16;
        async_ld16((const char*)(g + (size_t)(row0 + r0) * K + k0) + cb0,
                   (char*)s + wave * 1024);
        async_ld16((const char*)(g + (size_t)(row0 + r1) * K + k0) + cb1,
                   (char*)s + 4096 + wave * 1024);
    }
}

template<bool AF32, bool BF32, int MODE>
__global__ __launch_bounds__(256) void gemm_bt(const void* __restrict__ A,
                                               const void* __restrict__ B,
                                               void* __restrict__ C,
                                               bf16* __restrict__ Qp,
                                               bf16* __restrict__ Kp,
                                               bf16* __restrict__ Vp,
                                               int M, int N, int K) {
    __shared__ bf16 sA[128 * 32];
    __shared__ bf16 sB[128 * 32];
    const int tid  = threadIdx.x;
    const int lane = tid & 63;
    const int wave = tid >> 6;
    const int m0 = blockIdx.y * 128;
    const int n0 = blockIdx.x * 128;
    const int mrow = (wave >> 1) * 64;
    const int ncol = (wave & 1) * 64;

    f32x4 acc[4][4] = {};

    for (int k0 = 0; k0 < K; k0 += 32) {
        __syncthreads();
        stage_tile<AF32>(A, sA, m0, K, k0, tid);
        stage_tile<BF32>(B, sB, n0, K, k0, tid);
        __syncthreads();

        bf16x8 af[4], bfr[4];
        #pragma unroll
        for (int i = 0; i < 4; ++i)
            af[i] = *(const bf16x8*)&sA[(mrow + i * 16 + (lane & 15)) * 32 + (lane >> 4) * 8];
        #pragma unroll
        for (int j = 0; j < 4; ++j)
            bfr[j] = *(const bf16x8*)&sB[(ncol + j * 16 + (lane & 15)) * 32 + (lane >> 4) * 8];
        #pragma unroll
        for (int i = 0; i < 4; ++i)
            #pragma unroll
            for (int j = 0; j < 4; ++j)
                acc[i][j] = mfma_bf16(af[i], bfr[j], acc[i][j]);
    }

    #pragma unroll
    for (int i = 0; i < 4; ++i)
        #pragma unroll
        for (int j = 0; j < 4; ++j)
            #pragma unroll
            for (int r = 0; r < 4; ++r) {
                int row = m0 + mrow + i * 16 + (lane >> 4) * 4 + r;
                int col = n0 + ncol + j * 16 + (lane & 15);
                float fv = acc[i][j][r];
                if constexpr (MODE == 0) {
                    ((bf16*)C)[(size_t)row * N + col] = __float2bfloat16(fv);
                } else if constexpr (MODE == 1) {
                    ((bf16*)C)[(size_t)col * M + row] = __float2bfloat16(fv);
                } else if constexpr (MODE == 2) {
                    bf16 v = __float2bfloat16(fv);
                    if (col < 4096)      Qp[(size_t)row * 4096 + col] = v;
                    else if (col < 5120) Kp[(size_t)row * 1024 + (col - 4096)] = v;
                    else                 Vp[(size_t)(col - 5120) * 2048 + row] = v;
                } else {
                    ((float*)C)[(size_t)row * N + col] = fv;
                }
            }
}

// ---------------------------------------------------------------------------
// 8-phase GEMM (T3+T4+T2+T5): C = A[M,K] @ B[N,K]^T, bf16 sources.
// BM=256, BN=128, BK=64, 8 waves (512 thr), per-wave 64x64 output.
// Tri-buffered LDS K-tiles (3 x 48KB = 144KB). 4 phases per K-tile, each:
//   {8 ds_read_b128 -> stage-slice issue -> barrier -> lgkmcnt(0) ->
//    setprio(1) 8xMFMA setprio(0) -> [vmcnt(6) once per K-tile] -> barrier}
// Counted vmcnt (never 0 in main loop): stage t+2 while computing t;
// end-of-tile vmcnt(6) retires exactly tile t+1's 6 loads.
// XOR 16B-slot swizzle (phys = logical ^ (row&7)), applied on the global
// source at stage AND on the ds_read offset (both-sides involution).
// Requires K == 4096 (NT=64). MODE 2: QKV route. MODE 3: C f32 row-major.
// ---------------------------------------------------------------------------
#define VMW(N) asm volatile("s_waitcnt vmcnt(" #N ")" ::: "memory")

#define PH(SA, SB, MH, NH, STG, WT) do {                                          \
    bf16x8 aF[2][2], bF[2][2];                                                    \
    _Pragma("unroll") for (int i2 = 0; i2 < 2; ++i2)                              \
      _Pragma("unroll") for (int kh = 0; kh < 2; ++kh)                            \
        aF[i2][kh] = *(const bf16x8*)((SA) + offA[(MH)*2 + i2][kh]);              \
    _Pragma("unroll") for (int j2 = 0; j2 < 2; ++j2)                              \
      _Pragma("unroll") for (int kh = 0; kh < 2; ++kh)                            \
        bF[j2][kh] = *(const bf16x8*)((SB) + offB[(NH)*2 + j2][kh]);              \
    STG;                                                                          \
    __builtin_amdgcn_s_barrier();                                                 \
    asm volatile("s_waitcnt lgkmcnt(0)" ::: "memory");                            \
    __builtin_amdgcn_sched_barrier(0);                                            \
    __builtin_amdgcn_s_setprio(1);                                                \
    _Pragma("unroll") for (int i2 = 0; i2 < 2; ++i2)                              \
      _Pragma("unroll") for (int j2 = 0; j2 < 2; ++j2)                            \
        _Pragma("unroll") for (int kh = 0; kh < 2; ++kh)                          \
          acc[(MH)*2 + i2][(NH)*2 + j2] =                                         \
              mfma_bf16(aF[i2][kh], bF[j2][kh], acc[(MH)*2 + i2][(NH)*2 + j2]);   \
    __builtin_amdgcn_s_setprio(0);                                                \
    __builtin_amdgcn_sched_barrier(0);                                            \
    WT;                                                                           \
    __builtin_amdgcn_s_barrier();                                                 \
  } while (0)

#define TILE(SA, SB, SA2, SB2, T2, DOST, WT) do {                                 \
    PH(SA, SB, 0, 0, if (DOST) stgA01(SA2, T2), );                                \
    PH(SA, SB, 0, 1, if (DOST) stgA23(SA2, T2), );                                \
    PH(SA, SB, 1, 0, if (DOST) stgB0(SB2, T2), );                                 \
    PH(SA, SB, 1, 1, if (DOST) stgB1(SB2, T2), WT);                               \
  } while (0)

template<int MODE>
__global__ __launch_bounds__(512, 1) void gemm_8p(const bf16* __restrict__ A,
                                                  const bf16* __restrict__ B,
                                                  void* __restrict__ C,
                                                  bf16* __restrict__ Qp,
                                                  bf16* __restrict__ Kp,
                                                  bf16* __restrict__ Vp,
                                                  int M, int N, int K) {
    __shared__ __align__(16) bf16 sA0[16384], sA1[16384], sA2[16384];  // 256x64 each
    __shared__ __align__(16) bf16 sB0[8192],  sB1[8192],  sB2[8192];   // 128x64 each

    const int tid  = threadIdx.x;
    const int lane = tid & 63;
    const int wave = tid >> 6;          // 0..7
    const int wr   = wave >> 1;         // 0..3  (M strip of 64)
    const int wc   = wave & 1;          // 0..1  (N strip of 64)
    const int m0 = blockIdx.y * 256;
    const int n0 = blockIdx.x * 128;
    const int NT = K >> 6;              // 64 (K must be 4096)

    // ---- swizzled ds_read offsets (elems). logical 16B slot = kh*4 + (lane>>4);
    // phys = logical ^ (row & 7). Row stride 64 elems = 128B.
    int offA[4][2], offB[4][2];
    {
        const int l15 = lane & 15, l4 = lane >> 4;
        #pragma unroll
        for (int i = 0; i < 4; ++i) {
            const int ra = wr * 64 + i * 16 + l15;
            const int rb = wc * 64 + i * 16 + l15;
            #pragma unroll
            for (int kh = 0; kh < 2; ++kh) {
                offA[i][kh] = ra * 64 + (((kh * 4 + l4) ^ (ra & 7)) * 8);
                offB[i][kh] = rb * 64 + (((kh * 4 + l4) ^ (rb & 7)) * 8);
            }
        }
    }

    // ---- staging: thread u covers LDS linear slot u (row u>>3, 16B slot u&7);
    // global source pre-swizzled: logical slot = (u&7) ^ ((u>>3)&7).
    const int rloc = tid >> 3;                          // 0..63
    const int qsw  = (tid & 7) ^ (rloc & 7);            // pre-swizzled source slot
    const bf16* gA0 = A + (size_t)(m0 +   0 + rloc) * K + qsw * 8;
    const bf16* gA1 = A + (size_t)(m0 +  64 + rloc) * K + qsw * 8;
    const bf16* gA2 = A + (size_t)(m0 + 128 + rloc) * K + qsw * 8;
    const bf16* gA3 = A + (size_t)(m0 + 192 + rloc) * K + qsw * 8;
    const bf16* gB0 = B + (size_t)(n0 +   0 + rloc) * K + qsw * 8;
    const bf16* gB1 = B + (size_t)(n0 +  64 + rloc) * K + qsw * 8;
    const int w512 = wave * 512;   // wave-uniform LDS elem offset within a round

    auto stgA01 = [&](bf16* dst, int kt) __attribute__((always_inline)) {
        async_ld16(gA0 + kt * 64, dst + w512);
        async_ld16(gA1 + kt * 64, dst + 4096 + w512);
    };
    auto stgA23 = [&](bf16* dst, int kt) __attribute__((always_inline)) {
        async_ld16(gA2 + kt * 64, dst + 8192 + w512);
        async_ld16(gA3 + kt * 64, dst + 12288 + w512);
    };
    auto stgB0 = [&](bf16* dst, int kt) __attribute__((always_inline)) {
        async_ld16(gB0 + kt * 64, dst + w512);
    };
    auto stgB1 = [&](bf16* dst, int kt) __attribute__((always_inline)) {
        async_ld16(gB1 + kt * 64, dst + 4096 + w512);
    };

    f32x4 acc[4][4] = {};

    // ---- prologue: fully stage tiles 0,1 (12 loads); wait tile 0 (leave 6).
    stgA01(sA0, 0); stgA23(sA0, 0); stgB0(sB0, 0); stgB1(sB0, 0);
    stgA01(sA1, 1); stgA23(sA1, 1); stgB0(sB1, 1); stgB1(sB1, 1);
    VMW(6);
    __builtin_amdgcn_s_barrier();
    asm volatile("" ::: "memory");
    __builtin_amdgcn_sched_barrier(0);

    // ---- main loop: tiles t,t+1,t+2 from buf0/1/2; stage t+2,t+3,t+4.
    // Ledger: end of tile u has {u+1, u+2} in flight (12); vmcnt(6) retires u+1.
    int t = 0;
    for (; t < NT - 6; t += 3) {
        TILE(sA0, sB0, sA2, sB2, t + 2, true, VMW(6));
        TILE(sA1, sB1, sA0, sB0, t + 3, true, VMW(6));
        TILE(sA2, sB2, sA1, sB1, t + 4, true, VMW(6));
    }
    // ---- tail: tiles NT-4..NT-1 (t == NT-4 here), stages NT-2, NT-1.
    TILE(sA0, sB0, sA2, sB2, NT - 2, true,  VMW(6));   // tile NT-4
    TILE(sA1, sB1, sA0, sB0, NT - 1, true,  VMW(6));   // tile NT-3
    TILE(sA2, sB2, sA0, sB0, 0,      false, VMW(0));   // tile NT-2 (drain NT-1)
    TILE(sA0, sB0, sA1, sB1, 0,      false, );         // tile NT-1
    asm volatile("s_waitcnt vmcnt(0)" ::: "memory");   // safety drain

    // ---- epilogue
    #pragma unroll
    for (int i = 0; i < 4; ++i)
        #pragma unroll
        for (int j = 0; j < 4; ++j)
            #pragma unroll
            for (int r = 0; r < 4; ++r) {
                int row = m0 + wr * 64 + i * 16 + (lane >> 4) * 4 + r;
                int col = n0 + wc * 64 + j * 16 + (lane & 15);
                float fv = acc[i][j][r];
                if constexpr (MODE == 2) {
                    bf16 v = __float2bfloat16(fv);
                    if (col < 4096)      Qp[(size_t)row * 4096 + col] = v;
                    else if (col < 5120) Kp[(size_t)row * 1024 + (col - 4096)] = v;
                    else                 Vp[(size_t)(col - 5120) * 2048 + row] = v;
                } else {
                    ((float*)C)[(size_t)row * N + col] = fv;
                }
            }
}

// ---------------------------------------------------------------------------
// Merged RoPE: h<32 -> Q head h; h>=32 -> K head h-32. cos/sin f32 [T,64].
// ---------------------------------------------------------------------------
__global__ __launch_bounds__(256) void rope_all(bf16* __restrict__ Q,
                                                bf16* __restrict__ K,
                                                const float* __restrict__ cosp,
                                                const float* __restrict__ sinp,
                                                const int* __restrict__ spp) {
    int idx = blockIdx.x * blockDim.x + threadIdx.x;
    int d = idx & 63;
    int h = (idx >> 6) % 40;
    int t = idx / (64 * 40);
    int sp = *spp;
    float c = cosp[(size_t)(t + sp) * 64 + d];
    float s = sinp[(size_t)(t + sp) * 64 + d];
    bf16* row = (h < 32) ? (Q + (size_t)t * 4096 + h * 128)
                         : (K + (size_t)t * 1024 + (h - 32) * 128);
    float x1 = __bfloat162float(row[d]);
    float x2 = __bfloat162float(row[64 + d]);
    row[d]      = __float2bfloat16(x1 * c - x2 * s);
    row[64 + d] = __float2bfloat16(x2 * c + x1 * s);
}

// ---------------------------------------------------------------------------
// Flash attention, causal, T=2048, D=128, 32 Q heads, 8 KV heads (GQA 4:1).
// ---------------------------------------------------------------------------
#define NEG_SENT (-1.0e9f)
__global__ __launch_bounds__(256) void attn_k(const bf16* __restrict__ Q,
                                              const bf16* __restrict__ K,
                                              const bf16* __restrict__ VT,
                                              bf16* __restrict__ Y) {
    constexpr int SKS = 136;
    constexpr int SVS = 72;
    __shared__ bf16 sK[64 * SKS];    // 17408 B; P scratch aliases this
    __shared__ bf16 sVT[128 * SVS];  // 18432 B

    const int tid  = threadIdx.x;
    const int lane = tid & 63;
    const int wave = tid >> 6;
    const int qtile = 31 - (blockIdx.x >> 5);
    const int head  = blockIdx.x & 31;
    const int g     = head >> 2;
    const int qrow0 = qtile * 64 + wave * 16;
    bf16* sPw = sK + wave * 1152;

    bf16x8 qf[4];
    {
        const bf16* qbase = Q + (size_t)(qrow0 + (lane & 15)) * 4096 + head * 128;
        #pragma unroll
        for (int kk = 0; kk < 4; ++kk)
            qf[kk] = *(const bf16x8*)(qbase + kk * 32 + (lane >> 4) * 8);
    }

    float m_i[4], l_i[4];
    #pragma unroll
    for (int r = 0; r < 4; ++r) { m_i[r] = NEG_SENT; l_i[r] = 0.f; }
    f32x4 o[8] = {};
    const float scale = 0.08838834764831845f;

    for (int kt = 0; kt <= qtile; ++kt) {
        const int kt0 = kt * 64;
        __syncthreads();
        #pragma unroll
        for (int i = 0; i < 4; ++i) {
            int c = i * 256 + tid;
            {
                int row = c >> 4, ch = c & 15;
                *(uint4*)&sK[row * SKS + ch * 8] =
                    *(const uint4*)(K + (size_t)(kt0 + row) * 1024 + g * 128 + ch * 8);
            }
            {
                int row = c >> 3, ch = c & 7;
                *(uint4*)&sVT[row * SVS + ch * 8] =
                    *(const uint4*)(VT + (size_t)(g * 128 + row) * 2048 + kt0 + ch * 8);
            }
        }
        __syncthreads();

        f32x4 s[4];
        #pragma unroll
        for (int j = 0; j < 4; ++j) {
            f32x4 a = {};
            #pragma unroll
            for (int kk = 0; kk < 4; ++kk) {
                bf16x8 kfrag = *(const bf16x8*)&sK[(j * 16 + (lane & 15)) * SKS +
                                                   kk * 32 + (lane >> 4) * 8];
                a = mfma_bf16(qf[kk], kfrag, a);
            }
            s[j] = a;
        }

        #pragma unroll
        for (int j = 0; j < 4; ++j) {
            int tk = kt0 + j * 16 + (lane & 15);
            #pragma unroll
            for (int r = 0; r < 4; ++r) {
                int tq = qrow0 + (lane >> 4) * 4 + r;
                float v = s[j][r] * scale;
                s[j][r] = (tk > tq) ? NEG_SENT : v;
            }
        }

        #pragma unroll
        for (int r = 0; r < 4; ++r) {
            float mx = fmaxf(fmaxf(s[0][r], s[1][r]), fmaxf(s[2][r], s[3][r]));
            mx = redmax16(mx);
            float mn = fmaxf(m_i[r], mx);
            float alpha = sexp(m_i[r] - mn);
            m_i[r] = mn;
            float rs = 0.f;
            #pragma unroll
            for (int j = 0; j < 4; ++j) {
                float pv = sexp(s[j][r] - mn);
                s[j][r] = pv;
                rs += pv;
            }
            l_i[r] = l_i[r] * alpha + rs;
            #pragma unroll
            for (int j2 = 0; j2 < 8; ++j2) o[j2][r] *= alpha;
        }

        __syncthreads();

        #pragma unroll
        for (int j = 0; j < 4; ++j)
            #pragma unroll
            for (int r = 0; r < 4; ++r)
                sPw[((lane >> 4) * 4 + r) * SVS + j * 16 + (lane & 15)] =
                    __float2bfloat16(s[j][r]);
        __asm__ volatile("s_waitcnt lgkmcnt(0)" ::: "memory");

        #pragma unroll
        for (int kk2 = 0; kk2 < 2; ++kk2) {
            bf16x8 pf = *(const bf16x8*)&sPw[(lane & 15) * SVS + kk2 * 32 + (lane >> 4) * 8];
            #pragma unroll
            for (int j2 = 0; j2 < 8; ++j2) {
                bf16x8 vf = *(const bf16x8*)&sVT[(j2 * 16 + (lane & 15)) * SVS +
                                                 kk2 * 32 + (lane >> 4) * 8];
                o[j2] = mfma_bf16(pf, vf, o[j2]);
            }
        }
    }

    #pragma unroll
    for (int r = 0; r < 4; ++r) l_i[r] = redsum16(l_i[r]);
    #pragma unroll
    for (int j2 = 0; j2 < 8; ++j2)
        #pragma unroll
        for (int r = 0; r < 4; ++r) {
            int t   = qrow0 + (lane >> 4) * 4 + r;
            int col = head * 128 + j2 * 16 + (lane & 15);
            Y[(size_t)t * 4096 + col] = __float2bfloat16(o[j2][r] / l_i[r]);
        }
}

// ---------------------------------------------------------------------------
extern "C" void kernel_launch(void* const* d_in, const int* in_sizes, int n_in,
                              void* d_out, int out_size, void* d_ws, size_t ws_size,
                              hipStream_t stream) {
    const float* x    = (const float*)d_in[0];
    const float* cosp = (const float*)d_in[1];
    const float* sinp = (const float*)d_in[2];
    const float* wq   = (const float*)d_in[3];
    const float* wk   = (const float*)d_in[4];
    const float* wv   = (const float*)d_in[5];
    const float* wo   = (const float*)d_in[6];
    const int*   sp   = (const int*)d_in[7];
    float* out = (float*)d_out;

    char* ws = (char*)d_ws;
    bf16* Qb = (bf16*)d_out;   // 16 MB bf16 in the 32 MB f32 out buffer

    const size_t NEED = 92274688;   // 88 MiB
    if (ws_size >= NEED) {
        bf16* xb   = (bf16*)(ws);
        bf16* wqkv = (bf16*)(ws + (16u << 20));
        bf16* wob  = wqkv;                     // aliased; converted after QKV GEMM
        bf16* Kb   = (bf16*)(ws + (64u << 20));
        bf16* VT   = (bf16*)(ws + (68u << 20));
        bf16* Yb   = (bf16*)(ws + (72u << 20));

        cvt4_k<<<dim3(4096), 256, 0, stream>>>(x, xb, wq, wqkv,
                                               wk, wqkv + 16777216, wv, wqkv + 20971520);

        gemm_8p<2><<<dim3(48, 8), 512, 0, stream>>>(
            xb, wqkv, nullptr, Qb, Kb, VT, 2048, 6144, 4096);

        cvt_f32_bf16<<<dim3(4096), 256, 0, stream>>>(wo, wob, 2097152);

        rope_all<<<dim3(2048 * 40 * 64 / 256), 256, 0, stream>>>(Qb, Kb, cosp, sinp, sp);

        attn_k<<<dim3(1024), 256, 0, stream>>>(Qb, Kb, VT, Yb);

        gemm_8p<3><<<dim3(32, 8), 512, 0, stream>>>(
            Yb, wob, out, nullptr, nullptr, nullptr, 2048, 4096, 4096);
    } else {
        bf16* Kb = (bf16*)(ws);
        bf16* VT = (bf16*)(ws + (4u << 20));
        bf16* Yb = (bf16*)(ws + (8u << 20));

        gemm_bt<true, true, 0><<<dim3(32, 16), 256, 0, stream>>>(
            x, wq, Qb, nullptr, nullptr, nullptr, 2048, 4096, 4096);
        gemm_bt<true, true, 0><<<dim3(8, 16), 256, 0, stream>>>(
            x, wk, Kb, nullptr, nullptr, nullptr, 2048, 1024, 4096);
        gemm_bt<true, true, 1><<<dim3(8, 16), 256, 0, stream>>>(
            x, wv, VT, nullptr, nullptr, nullptr, 2048, 1024, 4096);

        rope_all<<<dim3(2048 * 40 * 64 / 256), 256, 0, stream>>>(Qb, Kb, cosp, sinp, sp);

        attn_k<<<dim3(1024), 256, 0, stream>>>(Qb, Kb, VT, Yb);

        gemm_bt<false, true, 3><<<dim3(32, 16), 256, 0, stream>>>(
            Yb, wo, out, nullptr, nullptr, nullptr, 2048, 4096, 4096);
    }
}

// Round 4
// 480.949 us; speedup vs baseline: 1.1823x; 1.1823x over previous
//
#include <hip/hip_runtime.h>
#include <hip/hip_bf16.h>
#include <stdint.h>

using bf16 = __hip_bfloat16;
using bf16x8 = __attribute__((ext_vector_type(8))) short;   // 8 bf16 = 4 VGPRs
using f32x4  = __attribute__((ext_vector_type(4))) float;

#define AS1 __attribute__((address_space(1)))
#define AS3 __attribute__((address_space(3)))

__device__ __forceinline__ void async_ld16(const void* g, void* l) {
    __builtin_amdgcn_global_load_lds((const AS1 void*)g, (AS3 void*)l, 16, 0, 0);
}

__device__ __forceinline__ f32x4 mfma_bf16(bf16x8 a, bf16x8 b, f32x4 c) {
    return __builtin_amdgcn_mfma_f32_16x16x32_bf16(a, b, c, 0, 0, 0);
}

__device__ __forceinline__ float sexp(float x) {
    return __expf(fmaxf(x, -80.0f));
}

// ---- 16-lane-group reductions: DPP row_shr (VALU) + one broadcast swizzle ----
template<int N> __device__ __forceinline__ float dpp_max16(float x) {
    int xi = __builtin_bit_cast(int, x);
    int yi = __builtin_amdgcn_update_dpp(xi, xi, 0x110 | N, 0xf, 0xf, false);
    return fmaxf(x, __builtin_bit_cast(float, yi));
}
template<int N> __device__ __forceinline__ float dpp_add16(float x) {
    int xi = __builtin_bit_cast(int, x);
    int yi = __builtin_amdgcn_update_dpp(0, xi, 0x110 | N, 0xf, 0xf, true);
    return x + __builtin_bit_cast(float, yi);
}
__device__ __forceinline__ float bcast15(float x) {
    return __builtin_bit_cast(float,
        __builtin_amdgcn_ds_swizzle(__builtin_bit_cast(int, x), 0x01F0));
}
__device__ __forceinline__ float redmax16(float x) {
    x = dpp_max16<1>(x); x = dpp_max16<2>(x);
    x = dpp_max16<4>(x); x = dpp_max16<8>(x);
    return bcast15(x);
}
__device__ __forceinline__ float redsum16(float x) {
    x = dpp_add16<1>(x); x = dpp_add16<2>(x);
    x = dpp_add16<4>(x); x = dpp_add16<8>(x);
    return bcast15(x);
}

// ---------------------------------------------------------------------------
// Merged f32->bf16 converts
// ---------------------------------------------------------------------------
__device__ __forceinline__ void cvt8(const float* p, bf16* d) {
    float4 lo = *(const float4*)p;
    float4 hi = *(const float4*)(p + 4);
    bf16 t8[8] = {__float2bfloat16(lo.x), __float2bfloat16(lo.y),
                  __float2bfloat16(lo.z), __float2bfloat16(lo.w),
                  __float2bfloat16(hi.x), __float2bfloat16(hi.y),
                  __float2bfloat16(hi.z), __float2bfloat16(hi.w)};
    *(bf16x8*)d = *(const bf16x8*)t8;
}

__global__ __launch_bounds__(256) void cvt4_k(const float* __restrict__ x,  bf16* __restrict__ xb,
                                              const float* __restrict__ wq, bf16* __restrict__ wqb,
                                              const float* __restrict__ wk, bf16* __restrict__ wkb,
                                              const float* __restrict__ wv, bf16* __restrict__ wvb) {
    int stride = gridDim.x * blockDim.x;
    for (int u = blockIdx.x * blockDim.x + threadIdx.x; u < 4194304; u += stride) {
        const float* s; bf16* d; size_t off;
        if (u < 1048576)      { s = x;  d = xb;  off = (size_t)u * 8; }
        else if (u < 3145728) { s = wq; d = wqb; off = (size_t)(u - 1048576) * 8; }
        else if (u < 3670016) { s = wk; d = wkb; off = (size_t)(u - 3145728) * 8; }
        else                  { s = wv; d = wvb; off = (size_t)(u - 3670016) * 8; }
        cvt8(s + off, d + off);
    }
}

__global__ __launch_bounds__(256) void cvt_f32_bf16(const float* __restrict__ src,
                                                    bf16* __restrict__ dst, int n8) {
    int stride = gridDim.x * blockDim.x;
    for (int u = blockIdx.x * blockDim.x + threadIdx.x; u < n8; u += stride)
        cvt8(src + (size_t)u * 8, dst + (size_t)u * 8);
}

// ---------------------------------------------------------------------------
// OLD simple GEMM (kept only for the no-workspace fallback, f32 sources).
// ---------------------------------------------------------------------------
template<bool SRCF32>
__device__ __forceinline__ void stage_tile(const void* __restrict__ src,
                                           bf16* __restrict__ s,
                                           int row0, int K, int k0, int tid) {
    if constexpr (SRCF32) {
        const float* g = (const float*)src;
        #pragma unroll
        for (int i = 0; i < 2; ++i) {
            int u = tid + 256 * i;
            int row = u >> 2, c8 = (u & 3) * 8;
            cvt8(g + (size_t)(row0 + row) * K + k0 + c8, &s[row * 32 + c8]);
        }
    } else {
        const bf16* g = (const bf16*)src;
        const int wave = tid >> 6, lane = tid & 63;
        const int c0 = wave * 64 + lane;
        const int r0 = c0 >> 2, cb0 = (c0 & 3) * 16;
        const int c1 = 256 + c0;
        const int r1 = c1 >> 2, cb1 = (c1 & 3) * 16;
        async_ld16((const char*)(g + (size_t)(row0 + r0) * K + k0) + cb0,
                   (char*)s + wave * 1024);
        async_ld16((const char*)(g + (size_t)(row0 + r1) * K + k0) + cb1,
                   (char*)s + 4096 + wave * 1024);
    }
}

template<bool AF32, bool BF32, int MODE>
__global__ __launch_bounds__(256) void gemm_bt(const void* __restrict__ A,
                                               const void* __restrict__ B,
                                               void* __restrict__ C,
                                               bf16* __restrict__ Qp,
                                               bf16* __restrict__ Kp,
                                               bf16* __restrict__ Vp,
                                               int M, int N, int K) {
    __shared__ bf16 sA[128 * 32];
    __shared__ bf16 sB[128 * 32];
    const int tid  = threadIdx.x;
    const int lane = tid & 63;
    const int wave = tid >> 6;
    const int m0 = blockIdx.y * 128;
    const int n0 = blockIdx.x * 128;
    const int mrow = (wave >> 1) * 64;
    const int ncol = (wave & 1) * 64;

    f32x4 acc[4][4] = {};

    for (int k0 = 0; k0 < K; k0 += 32) {
        __syncthreads();
        stage_tile<AF32>(A, sA, m0, K, k0, tid);
        stage_tile<BF32>(B, sB, n0, K, k0, tid);
        __syncthreads();

        bf16x8 af[4], bfr[4];
        #pragma unroll
        for (int i = 0; i < 4; ++i)
            af[i] = *(const bf16x8*)&sA[(mrow + i * 16 + (lane & 15)) * 32 + (lane >> 4) * 8];
        #pragma unroll
        for (int j = 0; j < 4; ++j)
            bfr[j] = *(const bf16x8*)&sB[(ncol + j * 16 + (lane & 15)) * 32 + (lane >> 4) * 8];
        #pragma unroll
        for (int i = 0; i < 4; ++i)
            #pragma unroll
            for (int j = 0; j < 4; ++j)
                acc[i][j] = mfma_bf16(af[i], bfr[j], acc[i][j]);
    }

    #pragma unroll
    for (int i = 0; i < 4; ++i)
        #pragma unroll
        for (int j = 0; j < 4; ++j)
            #pragma unroll
            for (int r = 0; r < 4; ++r) {
                int row = m0 + mrow + i * 16 + (lane >> 4) * 4 + r;
                int col = n0 + ncol + j * 16 + (lane & 15);
                float fv = acc[i][j][r];
                if constexpr (MODE == 0) {
                    ((bf16*)C)[(size_t)row * N + col] = __float2bfloat16(fv);
                } else if constexpr (MODE == 1) {
                    ((bf16*)C)[(size_t)col * M + row] = __float2bfloat16(fv);
                } else if constexpr (MODE == 2) {
                    bf16 v = __float2bfloat16(fv);
                    if (col < 4096)      Qp[(size_t)row * 4096 + col] = v;
                    else if (col < 5120) Kp[(size_t)row * 1024 + (col - 4096)] = v;
                    else                 Vp[(size_t)(col - 5120) * 2048 + row] = v;
                } else {
                    ((float*)C)[(size_t)row * N + col] = fv;
                }
            }
}

// ---------------------------------------------------------------------------
// 2-wait K-tile GEMM: C = A[M,K] @ B[N,K]^T, bf16 sources.
// BM=256, BN=128, BK=64, 8 waves (512 thr), per-wave 64x64 output.
// Tri-buffered LDS K-tiles (3 x 48KB = 144KB). Per K-tile (ONE barrier):
//   {8 ds_read kh0 | 8 ds_read kh1 | 6 stage loads ->
//    lgkmcnt(8) -> 16 MFMA kh0 (kh1 reads land under it) ->
//    lgkmcnt(0) -> 16 MFMA kh1 -> vmcnt(6) -> barrier}
// Each fragment read exactly ONCE per K-tile (16 b128/wave, ratio 0.5/MFMA).
// Counted vmcnt: stage t+2 while computing t; vmcnt(6) retires t+1's loads.
// XOR 16B-slot swizzle (phys = logical ^ (row&7)) on global source at stage
// AND on ds_read offsets (both-sides involution) -> 0 bank conflicts.
// Requires K == 4096 (NT=64). MODE 2: QKV route. MODE 3: C f32 row-major.
// ---------------------------------------------------------------------------
#define VMW(N) asm volatile("s_waitcnt vmcnt(" #N ")" ::: "memory")
#define SCB    __builtin_amdgcn_sched_barrier(0)

#define TILE2(SA, SB, SA2, SB2, T2, DOST, WT) do {                                \
    bf16x8 aF0[4], bF0[4], aF1[4], bF1[4];                                        \
    _Pragma("unroll") for (int i = 0; i < 4; ++i)                                 \
        aF0[i] = *(const bf16x8*)((SA) + offA[i][0]);                             \
    _Pragma("unroll") for (int j = 0; j < 4; ++j)                                 \
        bF0[j] = *(const bf16x8*)((SB) + offB[j][0]);                             \
    SCB;                                                                          \
    _Pragma("unroll") for (int i = 0; i < 4; ++i)                                 \
        aF1[i] = *(const bf16x8*)((SA) + offA[i][1]);                             \
    _Pragma("unroll") for (int j = 0; j < 4; ++j)                                 \
        bF1[j] = *(const bf16x8*)((SB) + offB[j][1]);                             \
    SCB;                                                                          \
    if (DOST) { stgA01(SA2, T2); stgA23(SA2, T2); stgB0(SB2, T2); stgB1(SB2, T2); } \
    asm volatile("s_waitcnt lgkmcnt(8)" ::: "memory");                            \
    SCB;                                                                          \
    __builtin_amdgcn_s_setprio(1);                                                \
    _Pragma("unroll") for (int i = 0; i < 4; ++i)                                 \
      _Pragma("unroll") for (int j = 0; j < 4; ++j)                               \
        acc[i][j] = mfma_bf16(aF0[i], bF0[j], acc[i][j]);                         \
    __builtin_amdgcn_s_setprio(0);                                                \
    SCB;                                                                          \
    asm volatile("s_waitcnt lgkmcnt(0)" ::: "memory");                            \
    SCB;                                                                          \
    __builtin_amdgcn_s_setprio(1);                                                \
    _Pragma("unroll") for (int i = 0; i < 4; ++i)                                 \
      _Pragma("unroll") for (int j = 0; j < 4; ++j)                               \
        acc[i][j] = mfma_bf16(aF1[i], bF1[j], acc[i][j]);                         \
    __builtin_amdgcn_s_setprio(0);                                                \
    SCB;                                                                          \
    WT;                                                                           \
    __builtin_amdgcn_s_barrier();                                                 \
  } while (0)

template<int MODE>
__global__ __launch_bounds__(512, 1) void gemm_8p(const bf16* __restrict__ A,
                                                  const bf16* __restrict__ B,
                                                  void* __restrict__ C,
                                                  bf16* __restrict__ Qp,
                                                  bf16* __restrict__ Kp,
                                                  bf16* __restrict__ Vp,
                                                  int M, int N, int K) {
    __shared__ __align__(16) bf16 sA0[16384], sA1[16384], sA2[16384];  // 256x64 each
    __shared__ __align__(16) bf16 sB0[8192],  sB1[8192],  sB2[8192];   // 128x64 each

    const int tid  = threadIdx.x;
    const int lane = tid & 63;
    const int wave = tid >> 6;          // 0..7
    const int wr   = wave >> 1;         // 0..3  (M strip of 64)
    const int wc   = wave & 1;          // 0..1  (N strip of 64)
    const int m0 = blockIdx.y * 256;
    const int n0 = blockIdx.x * 128;
    const int NT = K >> 6;              // 64 (K must be 4096)

    // ---- swizzled ds_read offsets (elems). logical 16B slot = kh*4 + (lane>>4);
    // phys = logical ^ (row & 7). Row stride 64 elems = 128B.
    int offA[4][2], offB[4][2];
    {
        const int l15 = lane & 15, l4 = lane >> 4;
        #pragma unroll
        for (int i = 0; i < 4; ++i) {
            const int ra = wr * 64 + i * 16 + l15;
            const int rb = wc * 64 + i * 16 + l15;
            #pragma unroll
            for (int kh = 0; kh < 2; ++kh) {
                offA[i][kh] = ra * 64 + (((kh * 4 + l4) ^ (ra & 7)) * 8);
                offB[i][kh] = rb * 64 + (((kh * 4 + l4) ^ (rb & 7)) * 8);
            }
        }
    }

    // ---- staging: thread u covers LDS linear slot u (row u>>3, 16B slot u&7);
    // global source pre-swizzled: logical slot = (u&7) ^ ((u>>3)&7).
    const int rloc = tid >> 3;                          // 0..63
    const int qsw  = (tid & 7) ^ (rloc & 7);            // pre-swizzled source slot
    const bf16* gA0 = A + (size_t)(m0 +   0 + rloc) * K + qsw * 8;
    const bf16* gA1 = A + (size_t)(m0 +  64 + rloc) * K + qsw * 8;
    const bf16* gA2 = A + (size_t)(m0 + 128 + rloc) * K + qsw * 8;
    const bf16* gA3 = A + (size_t)(m0 + 192 + rloc) * K + qsw * 8;
    const bf16* gB0 = B + (size_t)(n0 +   0 + rloc) * K + qsw * 8;
    const bf16* gB1 = B + (size_t)(n0 +  64 + rloc) * K + qsw * 8;
    const int w512 = wave * 512;   // wave-uniform LDS elem offset within a round

    auto stgA01 = [&](bf16* dst, int kt) __attribute__((always_inline)) {
        async_ld16(gA0 + kt * 64, dst + w512);
        async_ld16(gA1 + kt * 64, dst + 4096 + w512);
    };
    auto stgA23 = [&](bf16* dst, int kt) __attribute__((always_inline)) {
        async_ld16(gA2 + kt * 64, dst + 8192 + w512);
        async_ld16(gA3 + kt * 64, dst + 12288 + w512);
    };
    auto stgB0 = [&](bf16* dst, int kt) __attribute__((always_inline)) {
        async_ld16(gB0 + kt * 64, dst + w512);
    };
    auto stgB1 = [&](bf16* dst, int kt) __attribute__((always_inline)) {
        async_ld16(gB1 + kt * 64, dst + 4096 + w512);
    };

    f32x4 acc[4][4] = {};

    // ---- prologue: fully stage tiles 0,1 (12 loads); wait tile 0 (leave 6).
    stgA01(sA0, 0); stgA23(sA0, 0); stgB0(sB0, 0); stgB1(sB0, 0);
    stgA01(sA1, 1); stgA23(sA1, 1); stgB0(sB1, 1); stgB1(sB1, 1);
    VMW(6);
    __builtin_amdgcn_s_barrier();
    asm volatile("" ::: "memory");
    SCB;

    // ---- main loop: tiles t,t+1,t+2 from buf0/1/2; stage t+2,t+3,t+4.
    // Ledger: end of tile u has {u+1, u+2} in flight (12); vmcnt(6) retires u+1.
    int t = 0;
    for (; t < NT - 6; t += 3) {
        TILE2(sA0, sB0, sA2, sB2, t + 2, true, VMW(6));
        TILE2(sA1, sB1, sA0, sB0, t + 3, true, VMW(6));
        TILE2(sA2, sB2, sA1, sB1, t + 4, true, VMW(6));
    }
    // ---- tail: tiles NT-4..NT-1 (t == NT-4 here), stages NT-2, NT-1.
    TILE2(sA0, sB0, sA2, sB2, NT - 2, true,  VMW(6));   // tile NT-4
    TILE2(sA1, sB1, sA0, sB0, NT - 1, true,  VMW(6));   // tile NT-3
    TILE2(sA2, sB2, sA0, sB0, 0,      false, VMW(0));   // tile NT-2 (drain NT-1)
    TILE2(sA0, sB0, sA1, sB1, 0,      false, );         // tile NT-1
    asm volatile("s_waitcnt vmcnt(0)" ::: "memory");   // safety drain

    // ---- epilogue
    #pragma unroll
    for (int i = 0; i < 4; ++i)
        #pragma unroll
        for (int j = 0; j < 4; ++j)
            #pragma unroll
            for (int r = 0; r < 4; ++r) {
                int row = m0 + wr * 64 + i * 16 + (lane >> 4) * 4 + r;
                int col = n0 + wc * 64 + j * 16 + (lane & 15);
                float fv = acc[i][j][r];
                if constexpr (MODE == 2) {
                    bf16 v = __float2bfloat16(fv);
                    if (col < 4096)      Qp[(size_t)row * 4096 + col] = v;
                    else if (col < 5120) Kp[(size_t)row * 1024 + (col - 4096)] = v;
                    else                 Vp[(size_t)(col - 5120) * 2048 + row] = v;
                } else {
                    ((float*)C)[(size_t)row * N + col] = fv;
                }
            }
}

// ---------------------------------------------------------------------------
// Merged RoPE: h<32 -> Q head h; h>=32 -> K head h-32. cos/sin f32 [T,64].
// ---------------------------------------------------------------------------
__global__ __launch_bounds__(256) void rope_all(bf16* __restrict__ Q,
                                                bf16* __restrict__ K,
                                                const float* __restrict__ cosp,
                                                const float* __restrict__ sinp,
                                                const int* __restrict__ spp) {
    int idx = blockIdx.x * blockDim.x + threadIdx.x;
    int d = idx & 63;
    int h = (idx >> 6) % 40;
    int t = idx / (64 * 40);
    int sp = *spp;
    float c = cosp[(size_t)(t + sp) * 64 + d];
    float s = sinp[(size_t)(t + sp) * 64 + d];
    bf16* row = (h < 32) ? (Q + (size_t)t * 4096 + h * 128)
                         : (K + (size_t)t * 1024 + (h - 32) * 128);
    float x1 = __bfloat162float(row[d]);
    float x2 = __bfloat162float(row[64 + d]);
    row[d]      = __float2bfloat16(x1 * c - x2 * s);
    row[64 + d] = __float2bfloat16(x2 * c + x1 * s);
}

// ---------------------------------------------------------------------------
// Flash attention, causal, T=2048, D=128, 32 Q heads, 8 KV heads (GQA 4:1).
// ---------------------------------------------------------------------------
#define NEG_SENT (-1.0e9f)
__global__ __launch_bounds__(256) void attn_k(const bf16* __restrict__ Q,
                                              const bf16* __restrict__ K,
                                              const bf16* __restrict__ VT,
                                              bf16* __restrict__ Y) {
    constexpr int SKS = 136;
    constexpr int SVS = 72;
    __shared__ bf16 sK[64 * SKS];    // 17408 B; P scratch aliases this
    __shared__ bf16 sVT[128 * SVS];  // 18432 B

    const int tid  = threadIdx.x;
    const int lane = tid & 63;
    const int wave = tid >> 6;
    const int qtile = 31 - (blockIdx.x >> 5);
    const int head  = blockIdx.x & 31;
    const int g     = head >> 2;
    const int qrow0 = qtile * 64 + wave * 16;
    bf16* sPw = sK + wave * 1152;

    bf16x8 qf[4];
    {
        const bf16* qbase = Q + (size_t)(qrow0 + (lane & 15)) * 4096 + head * 128;
        #pragma unroll
        for (int kk = 0; kk < 4; ++kk)
            qf[kk] = *(const bf16x8*)(qbase + kk * 32 + (lane >> 4) * 8);
    }

    float m_i[4], l_i[4];
    #pragma unroll
    for (int r = 0; r < 4; ++r) { m_i[r] = NEG_SENT; l_i[r] = 0.f; }
    f32x4 o[8] = {};
    const float scale = 0.08838834764831845f;

    for (int kt = 0; kt <= qtile; ++kt) {
        const int kt0 = kt * 64;
        __syncthreads();
        #pragma unroll
        for (int i = 0; i < 4; ++i) {
            int c = i * 256 + tid;
            {
                int row = c >> 4, ch = c & 15;
                *(uint4*)&sK[row * SKS + ch * 8] =
                    *(const uint4*)(K + (size_t)(kt0 + row) * 1024 + g * 128 + ch * 8);
            }
            {
                int row = c >> 3, ch = c & 7;
                *(uint4*)&sVT[row * SVS + ch * 8] =
                    *(const uint4*)(VT + (size_t)(g * 128 + row) * 2048 + kt0 + ch * 8);
            }
        }
        __syncthreads();

        f32x4 s[4];
        #pragma unroll
        for (int j = 0; j < 4; ++j) {
            f32x4 a = {};
            #pragma unroll
            for (int kk = 0; kk < 4; ++kk) {
                bf16x8 kfrag = *(const bf16x8*)&sK[(j * 16 + (lane & 15)) * SKS +
                                                   kk * 32 + (lane >> 4) * 8];
                a = mfma_bf16(qf[kk], kfrag, a);
            }
            s[j] = a;
        }

        #pragma unroll
        for (int j = 0; j < 4; ++j) {
            int tk = kt0 + j * 16 + (lane & 15);
            #pragma unroll
            for (int r = 0; r < 4; ++r) {
                int tq = qrow0 + (lane >> 4) * 4 + r;
                float v = s[j][r] * scale;
                s[j][r] = (tk > tq) ? NEG_SENT : v;
            }
        }

        #pragma unroll
        for (int r = 0; r < 4; ++r) {
            float mx = fmaxf(fmaxf(s[0][r], s[1][r]), fmaxf(s[2][r], s[3][r]));
            mx = redmax16(mx);
            float mn = fmaxf(m_i[r], mx);
            float alpha = sexp(m_i[r] - mn);
            m_i[r] = mn;
            float rs = 0.f;
            #pragma unroll
            for (int j = 0; j < 4; ++j) {
                float pv = sexp(s[j][r] - mn);
                s[j][r] = pv;
                rs += pv;
            }
            l_i[r] = l_i[r] * alpha + rs;
            #pragma unroll
            for (int j2 = 0; j2 < 8; ++j2) o[j2][r] *= alpha;
        }

        __syncthreads();

        #pragma unroll
        for (int j = 0; j < 4; ++j)
            #pragma unroll
            for (int r = 0; r < 4; ++r)
                sPw[((lane >> 4) * 4 + r) * SVS + j * 16 + (lane & 15)] =
                    __float2bfloat16(s[j][r]);
        __asm__ volatile("s_waitcnt lgkmcnt(0)" ::: "memory");

        #pragma unroll
        for (int kk2 = 0; kk2 < 2; ++kk2) {
            bf16x8 pf = *(const bf16x8*)&sPw[(lane & 15) * SVS + kk2 * 32 + (lane >> 4) * 8];
            #pragma unroll
            for (int j2 = 0; j2 < 8; ++j2) {
                bf16x8 vf = *(const bf16x8*)&sVT[(j2 * 16 + (lane & 15)) * SVS +
                                                 kk2 * 32 + (lane >> 4) * 8];
                o[j2] = mfma_bf16(pf, vf, o[j2]);
            }
        }
    }

    #pragma unroll
    for (int r = 0; r < 4; ++r) l_i[r] = redsum16(l_i[r]);
    #pragma unroll
    for (int j2 = 0; j2 < 8; ++j2)
        #pragma unroll
        for (int r = 0; r < 4; ++r) {
            int t   = qrow0 + (lane >> 4) * 4 + r;
            int col = head * 128 + j2 * 16 + (lane & 15);
            Y[(size_t)t * 4096 + col] = __float2bfloat16(o[j2][r] / l_i[r]);
        }
}

// ---------------------------------------------------------------------------
extern "C" void kernel_launch(void* const* d_in, const int* in_sizes, int n_in,
                              void* d_out, int out_size, void* d_ws, size_t ws_size,
                              hipStream_t stream) {
    const float* x    = (const float*)d_in[0];
    const float* cosp = (const float*)d_in[1];
    const float* sinp = (const float*)d_in[2];
    const float* wq   = (const float*)d_in[3];
    const float* wk   = (const float*)d_in[4];
    const float* wv   = (const float*)d_in[5];
    const float* wo   = (const float*)d_in[6];
    const int*   sp   = (const int*)d_in[7];
    float* out = (float*)d_out;

    char* ws = (char*)d_ws;
    bf16* Qb = (bf16*)d_out;   // 16 MB bf16 in the 32 MB f32 out buffer

    const size_t NEED = 92274688;   // 88 MiB
    if (ws_size >= NEED) {
        bf16* xb   = (bf16*)(ws);
        bf16* wqkv = (bf16*)(ws + (16u << 20));
        bf16* wob  = wqkv;                     // aliased; converted after QKV GEMM
        bf16* Kb   = (bf16*)(ws + (64u << 20));
        bf16* VT   = (bf16*)(ws + (68u << 20));
        bf16* Yb   = (bf16*)(ws + (72u << 20));

        cvt4_k<<<dim3(4096), 256, 0, stream>>>(x, xb, wq, wqkv,
                                               wk, wqkv + 16777216, wv, wqkv + 20971520);

        gemm_8p<2><<<dim3(48, 8), 512, 0, stream>>>(
            xb, wqkv, nullptr, Qb, Kb, VT, 2048, 6144, 4096);

        cvt_f32_bf16<<<dim3(4096), 256, 0, stream>>>(wo, wob, 2097152);

        rope_all<<<dim3(2048 * 40 * 64 / 256), 256, 0, stream>>>(Qb, Kb, cosp, sinp, sp);

        attn_k<<<dim3(1024), 256, 0, stream>>>(Qb, Kb, VT, Yb);

        gemm_8p<3><<<dim3(32, 8), 512, 0, stream>>>(
            Yb, wob, out, nullptr, nullptr, nullptr, 2048, 4096, 4096);
    } else {
        bf16* Kb = (bf16*)(ws);
        bf16* VT = (bf16*)(ws + (4u << 20));
        bf16* Yb = (bf16*)(ws + (8u << 20));

        gemm_bt<true, true, 0><<<dim3(32, 16), 256, 0, stream>>>(
            x, wq, Qb, nullptr, nullptr, nullptr, 2048, 4096, 4096);
        gemm_bt<true, true, 0><<<dim3(8, 16), 256, 0, stream>>>(
            x, wk, Kb, nullptr, nullptr, nullptr, 2048, 1024, 4096);
        gemm_bt<true, true, 1><<<dim3(8, 16), 256, 0, stream>>>(
            x, wv, VT, nullptr, nullptr, nullptr, 2048, 1024, 4096);

        rope_all<<<dim3(2048 * 40 * 64 / 256), 256, 0, stream>>>(Qb, Kb, cosp, sinp, sp);

        attn_k<<<dim3(1024), 256, 0, stream>>>(Qb, Kb, VT, Yb);

        gemm_bt<false, true, 3><<<dim3(32, 16), 256, 0, stream>>>(
            Yb, wo, out, nullptr, nullptr, nullptr, 2048, 4096, 4096);
    }
}